// Round 1
// baseline (793.304 us; speedup 1.0000x reference)
//
#include <hip/hip_runtime.h>

#define BDIM 2
#define SDIM 2048
#define DDIM 2048
#define HQ 16
#define HKV 4
#define DKH 128
#define NKV 512     // HKV*DKH
#define MROWS 4096  // B*S

typedef __attribute__((ext_vector_type(8))) short bf16x8;
typedef __attribute__((ext_vector_type(4))) float f32x4;
typedef __attribute__((ext_vector_type(8))) unsigned short u16x8;
typedef __attribute__((ext_vector_type(4))) unsigned short u16x4;

__device__ __forceinline__ unsigned short f2bf(float f) {
    union { float f; unsigned int u; } v; v.f = f;
    unsigned int r = v.u + 0x7FFFu + ((v.u >> 16) & 1u);
    return (unsigned short)(r >> 16);
}

// ---------------- cast f32 -> bf16 ----------------
__global__ void cast_f32_to_bf16(const float* __restrict__ in,
                                 unsigned short* __restrict__ out, int n) {
    int i = (blockIdx.x * blockDim.x + threadIdx.x) * 4;
    if (i >= n) return;
    float4 v = *(const float4*)(in + i);
    u16x4 o;
    o[0] = f2bf(v.x); o[1] = f2bf(v.y); o[2] = f2bf(v.z); o[3] = f2bf(v.w);
    *(u16x4*)(out + i) = o;
}

// ---------------- RoPE (f32 in, bf16 out), folds optional scale ----------------
__global__ void rope_bf16(const float* __restrict__ in,
                          const float* __restrict__ cosT,
                          const float* __restrict__ sinT,
                          unsigned short* __restrict__ out,
                          int rowlen, float oscale) {
    int r = blockIdx.x;             // 0..MROWS-1
    int pos = r & (SDIM - 1);       // seq position
    const float* rowp = in + (size_t)r * rowlen;
    unsigned short* orow = out + (size_t)r * rowlen;
    for (int p = threadIdx.x; p < (rowlen >> 1); p += blockDim.x) {
        int hh = p >> 6, i = p & 63;        // head, pair index
        int base = hh * 128 + i * 2;
        float xr = rowp[base], xi = rowp[base + 1];
        float c = cosT[pos * 64 + i], s = sinT[pos * 64 + i];
        orow[base]     = f2bf((xr * c - xi * s) * oscale);
        orow[base + 1] = f2bf((xr * s + xi * c) * oscale);
    }
}

// ---------------- GEMM: C[M,N] = A[M,K] * B[N,K]^T + bias (m97 recipe) ----------------
__global__ __launch_bounds__(256) void gemm_bt(
    const unsigned short* __restrict__ A,
    const unsigned short* __restrict__ Bm,
    const float* __restrict__ bias,
    float* __restrict__ C,
    int Mdim, int Ndim, int Kdim) {
    __shared__ unsigned short As[128 * 32];
    __shared__ unsigned short Bs[128 * 32];
    const int tid = threadIdx.x;
    const int w = tid >> 6, lane = tid & 63;
    const int ml = lane & 15, quad = lane >> 4;
    const int m0 = blockIdx.y * 128, n0 = blockIdx.x * 128;
    const int wr = (w >> 1) * 64, wc = (w & 1) * 64;

    f32x4 acc[4][4] = {};

    const int c0 = tid, c1 = tid + 256;
    const int ar0 = c0 >> 2, ak0 = (c0 & 3) * 8;
    const int ar1 = c1 >> 2, ak1 = (c1 & 3) * 8;

    for (int kt = 0; kt < Kdim; kt += 32) {
        __builtin_amdgcn_global_load_lds(
            (const __attribute__((address_space(1))) unsigned int*)(A + (size_t)(m0 + ar0) * Kdim + kt + ak0),
            (__attribute__((address_space(3))) unsigned int*)(As + c0 * 8), 16, 0, 0);
        __builtin_amdgcn_global_load_lds(
            (const __attribute__((address_space(1))) unsigned int*)(A + (size_t)(m0 + ar1) * Kdim + kt + ak1),
            (__attribute__((address_space(3))) unsigned int*)(As + c1 * 8), 16, 0, 0);
        __builtin_amdgcn_global_load_lds(
            (const __attribute__((address_space(1))) unsigned int*)(Bm + (size_t)(n0 + ar0) * Kdim + kt + ak0),
            (__attribute__((address_space(3))) unsigned int*)(Bs + c0 * 8), 16, 0, 0);
        __builtin_amdgcn_global_load_lds(
            (const __attribute__((address_space(1))) unsigned int*)(Bm + (size_t)(n0 + ar1) * Kdim + kt + ak1),
            (__attribute__((address_space(3))) unsigned int*)(Bs + c1 * 8), 16, 0, 0);
        __syncthreads();

        bf16x8 af[4], bfr[4];
#pragma unroll
        for (int i = 0; i < 4; ++i)
            af[i] = *(const bf16x8*)&As[(wr + i * 16 + ml) * 32 + quad * 8];
#pragma unroll
        for (int j = 0; j < 4; ++j)
            bfr[j] = *(const bf16x8*)&Bs[(wc + j * 16 + ml) * 32 + quad * 8];
#pragma unroll
        for (int i = 0; i < 4; ++i)
#pragma unroll
            for (int j = 0; j < 4; ++j)
                acc[i][j] = __builtin_amdgcn_mfma_f32_16x16x32_bf16(af[i], bfr[j], acc[i][j], 0, 0, 0);
        __syncthreads();
    }

#pragma unroll
    for (int j = 0; j < 4; ++j) {
        int col = n0 + wc + j * 16 + ml;
        float bj = bias[col];
#pragma unroll
        for (int i = 0; i < 4; ++i) {
            int row0 = m0 + wr + i * 16 + quad * 4;
#pragma unroll
            for (int r = 0; r < 4; ++r)
                C[(size_t)(row0 + r) * Ndim + col] = acc[i][j][r] + bj;
        }
    }
}

// ---------------- Flash attention (causal, GQA), bf16 in/out ----------------
// Q: [MROWS, DDIM] (scale pre-folded), K: [MROWS, NKV], V: [MROWS, NKV], O: [MROWS, DDIM]
__global__ __launch_bounds__(256) void attn_fwd(
    const unsigned short* __restrict__ Q,
    const unsigned short* __restrict__ K,
    const unsigned short* __restrict__ V,
    unsigned short* __restrict__ O) {
    const int qt = blockIdx.x;  // q tile (64 rows)
    const int h  = blockIdx.y;  // query head
    const int b  = blockIdx.z;  // batch
    const int g  = h >> 2;      // kv head (REP=4)
    const int tid = threadIdx.x;
    const int w = tid >> 6, lane = tid & 63;
    const int ml = lane & 15, quad = lane >> 4;

    __shared__ unsigned short Qs[64 * 136];   // padded rows (136) keep 16B align, 2-way banks
    __shared__ unsigned short Ks[32 * 136];
    __shared__ unsigned short Vts[128 * 40];  // V transposed [d][s], padded to 40
    __shared__ unsigned short Ps[4 * 16 * 32];

    // stage Q tile (64 x 128)
#pragma unroll
    for (int kk = 0; kk < 4; ++kk) {
        int cc = tid + kk * 256;
        int row = cc >> 4, c8 = (cc & 15) * 8;
        u16x8 v = *(const u16x8*)(Q + (size_t)(b * SDIM + qt * 64 + row) * DDIM + h * DKH + c8);
        *(u16x8*)&Qs[row * 136 + c8] = v;
    }

    float m_run[4], l_run[4];
    f32x4 o_acc[8];
#pragma unroll
    for (int r = 0; r < 4; ++r) { m_run[r] = -INFINITY; l_run[r] = 0.f; }
#pragma unroll
    for (int d = 0; d < 8; ++d) o_acc[d] = (f32x4){0.f, 0.f, 0.f, 0.f};

    const int q_base = qt * 64 + w * 16 + quad * 4;  // + r gives global q row (within seq)
    const int kt_end = qt * 2 + 2;

    for (int kt = 0; kt < kt_end; ++kt) {
        __syncthreads();  // protect Ks/Vts from previous iteration's readers
        // stage K (32x128) and V^T (128x32)
#pragma unroll
        for (int kk = 0; kk < 2; ++kk) {
            int cc = tid + kk * 256;
            int row = cc >> 4, c8 = (cc & 15) * 8;
            size_t gidx = (size_t)(b * SDIM + kt * 32 + row) * NKV + g * DKH + c8;
            u16x8 kv = *(const u16x8*)(K + gidx);
            *(u16x8*)&Ks[row * 136 + c8] = kv;
            u16x8 vv = *(const u16x8*)(V + gidx);
#pragma unroll
            for (int e = 0; e < 8; ++e)
                Vts[(c8 + e) * 40 + row] = vv[e];
        }
        __syncthreads();

        // QK^T: 16 q-rows x 32 k-cols per wave
        bf16x8 aq[4];
#pragma unroll
        for (int kc = 0; kc < 4; ++kc)
            aq[kc] = *(const bf16x8*)&Qs[(w * 16 + ml) * 136 + kc * 32 + quad * 8];

        f32x4 s[2];
#pragma unroll
        for (int nt = 0; nt < 2; ++nt) {
            f32x4 sc = (f32x4){0.f, 0.f, 0.f, 0.f};
#pragma unroll
            for (int kc = 0; kc < 4; ++kc) {
                bf16x8 bk = *(const bf16x8*)&Ks[(nt * 16 + ml) * 136 + kc * 32 + quad * 8];
                sc = __builtin_amdgcn_mfma_f32_16x16x32_bf16(aq[kc], bk, sc, 0, 0, 0);
            }
            s[nt] = sc;
        }

        // causal mask + online softmax (row = q_base + r, col = kt*32 + nt*16 + ml)
        float sv[2][4], mx[4];
#pragma unroll
        for (int r = 0; r < 4; ++r) mx[r] = -INFINITY;
#pragma unroll
        for (int nt = 0; nt < 2; ++nt) {
            int kcol = kt * 32 + nt * 16 + ml;
#pragma unroll
            for (int r = 0; r < 4; ++r) {
                float x = s[nt][r];
                if (kcol > q_base + r) x = -INFINITY;
                sv[nt][r] = x;
                mx[r] = fmaxf(mx[r], x);
            }
        }
#pragma unroll
        for (int r = 0; r < 4; ++r) {
            mx[r] = fmaxf(mx[r], __shfl_xor(mx[r], 1));
            mx[r] = fmaxf(mx[r], __shfl_xor(mx[r], 2));
            mx[r] = fmaxf(mx[r], __shfl_xor(mx[r], 4));
            mx[r] = fmaxf(mx[r], __shfl_xor(mx[r], 8));
        }

        float m_new[4], alpha[4], lad[4];
#pragma unroll
        for (int r = 0; r < 4; ++r) {
            m_new[r] = fmaxf(m_run[r], mx[r]);
            alpha[r] = __expf(m_run[r] - m_new[r]);
            lad[r] = 0.f;
        }
#pragma unroll
        for (int nt = 0; nt < 2; ++nt)
#pragma unroll
            for (int r = 0; r < 4; ++r) {
                float p = __expf(sv[nt][r] - m_new[r]);
                lad[r] += p;
                Ps[w * 512 + (quad * 4 + r) * 32 + nt * 16 + ml] = f2bf(p);
            }
#pragma unroll
        for (int r = 0; r < 4; ++r) {
            lad[r] += __shfl_xor(lad[r], 1);
            lad[r] += __shfl_xor(lad[r], 2);
            lad[r] += __shfl_xor(lad[r], 4);
            lad[r] += __shfl_xor(lad[r], 8);
            l_run[r] = l_run[r] * alpha[r] + lad[r];
            m_run[r] = m_new[r];
        }
#pragma unroll
        for (int d = 0; d < 8; ++d)
#pragma unroll
            for (int r = 0; r < 4; ++r)
                o_acc[d][r] *= alpha[r];

        // PV: P (A-layout via LDS round-trip) x V^T tiles
        bf16x8 ap = *(const bf16x8*)&Ps[w * 512 + ml * 32 + quad * 8];
#pragma unroll
        for (int d = 0; d < 8; ++d) {
            bf16x8 bv = *(const bf16x8*)&Vts[(d * 16 + ml) * 40 + quad * 8];
            o_acc[d] = __builtin_amdgcn_mfma_f32_16x16x32_bf16(ap, bv, o_acc[d], 0, 0, 0);
        }
    }

    // epilogue: normalize and store
#pragma unroll
    for (int d = 0; d < 8; ++d)
#pragma unroll
        for (int r = 0; r < 4; ++r) {
            float ov = o_acc[d][r] / l_run[r];
            O[(size_t)(b * SDIM + q_base + r) * DDIM + h * DKH + d * 16 + ml] = f2bf(ov);
        }
}

// ---------------- host launch ----------------
extern "C" void kernel_launch(void* const* d_in, const int* in_sizes, int n_in,
                              void* d_out, int out_size, void* d_ws, size_t ws_size,
                              hipStream_t stream) {
    const float* x    = (const float*)d_in[0];
    const float* fcos = (const float*)d_in[1];
    const float* fsin = (const float*)d_in[2];
    const float* wq_w = (const float*)d_in[3];
    const float* wq_b = (const float*)d_in[4];
    const float* wk_w = (const float*)d_in[5];
    const float* wk_b = (const float*)d_in[6];
    const float* wv_w = (const float*)d_in[7];
    const float* wv_b = (const float*)d_in[8];
    const float* wo_w = (const float*)d_in[9];
    const float* wo_b = (const float*)d_in[10];
    float* out = (float*)d_out;

    char* ws = (char*)d_ws;
    size_t off = 0;
    auto alloc = [&](size_t bytes) {
        char* p = ws + off;
        off += (bytes + 255) & ~(size_t)255;
        return p;
    };
    unsigned short* xb  = (unsigned short*)alloc((size_t)MROWS * DDIM * 2);
    unsigned short* wqb = (unsigned short*)alloc((size_t)DDIM * DDIM * 2);
    unsigned short* wkb = (unsigned short*)alloc((size_t)NKV * DDIM * 2);
    unsigned short* wvb = (unsigned short*)alloc((size_t)NKV * DDIM * 2);
    unsigned short* wob = (unsigned short*)alloc((size_t)DDIM * DDIM * 2);
    float* qf = (float*)alloc((size_t)MROWS * DDIM * 4);
    float* kf = (float*)alloc((size_t)MROWS * NKV * 4);
    float* vf = (float*)alloc((size_t)MROWS * NKV * 4);
    unsigned short* qr  = (unsigned short*)alloc((size_t)MROWS * DDIM * 2);
    unsigned short* kr  = (unsigned short*)alloc((size_t)MROWS * NKV * 2);
    unsigned short* vb  = (unsigned short*)alloc((size_t)MROWS * NKV * 2);
    unsigned short* att = (unsigned short*)qf;  // reuse qf region (free after rope_q)

    auto cast_launch = [&](const float* in, unsigned short* o, int n) {
        int blocks = (n / 4 + 255) / 256;
        cast_f32_to_bf16<<<dim3(blocks), dim3(256), 0, stream>>>(in, o, n);
    };
    cast_launch(x,    xb,  MROWS * DDIM);
    cast_launch(wq_w, wqb, DDIM * DDIM);
    cast_launch(wk_w, wkb, NKV * DDIM);
    cast_launch(wv_w, wvb, NKV * DDIM);
    cast_launch(wo_w, wob, DDIM * DDIM);

    gemm_bt<<<dim3(DDIM / 128, MROWS / 128), 256, 0, stream>>>(xb, wqb, wq_b, qf, MROWS, DDIM, DDIM);
    gemm_bt<<<dim3(NKV / 128,  MROWS / 128), 256, 0, stream>>>(xb, wkb, wk_b, kf, MROWS, NKV, DDIM);
    gemm_bt<<<dim3(NKV / 128,  MROWS / 128), 256, 0, stream>>>(xb, wvb, wv_b, vf, MROWS, NKV, DDIM);

    const float scale = 0.08838834764831845f;  // 1/sqrt(128), folded into Q
    rope_bf16<<<dim3(MROWS), dim3(256), 0, stream>>>(qf, fcos, fsin, qr, DDIM, scale);
    rope_bf16<<<dim3(MROWS), dim3(256), 0, stream>>>(kf, fcos, fsin, kr, NKV, 1.0f);
    cast_launch(vf, vb, MROWS * NKV);

    attn_fwd<<<dim3(SDIM / 64, HQ, BDIM), 256, 0, stream>>>(qr, kr, vb, att);

    gemm_bt<<<dim3(DDIM / 128, MROWS / 128), 256, 0, stream>>>(att, wob, wo_b, out, MROWS, DDIM, DDIM);
}

// Round 2
// 430.743 us; speedup vs baseline: 1.8417x; 1.8417x over previous
//
#include <hip/hip_runtime.h>

#define BDIM 2
#define SDIM 2048
#define DDIM 2048
#define HQ 16
#define HKV 4
#define DKH 128
#define NKV 512      // HKV*DKH
#define NQKV 3072    // DDIM + 2*NKV
#define MROWS 4096   // B*S

typedef __attribute__((ext_vector_type(8))) short bf16x8;
typedef __attribute__((ext_vector_type(4))) float f32x4;
typedef __attribute__((ext_vector_type(8))) unsigned short u16x8;
typedef __attribute__((ext_vector_type(4))) unsigned short u16x4;

#define AS1 __attribute__((address_space(1)))
#define AS3 __attribute__((address_space(3)))

__device__ __forceinline__ unsigned short f2bf(float f) {
    union { float f; unsigned int u; } v; v.f = f;
    unsigned int r = v.u + 0x7FFFu + ((v.u >> 16) & 1u);
    return (unsigned short)(r >> 16);
}
__device__ __forceinline__ float bf2f(unsigned short u) {
    union { unsigned int u; float f; } v; v.u = ((unsigned int)u) << 16;
    return v.f;
}

// ---------------- cast f32 -> bf16 ----------------
__global__ void cast_f32_to_bf16(const float* __restrict__ in,
                                 unsigned short* __restrict__ out, int n) {
    int i = (blockIdx.x * blockDim.x + threadIdx.x) * 4;
    if (i >= n) return;
    float4 v = *(const float4*)(in + i);
    u16x4 o;
    o[0] = f2bf(v.x); o[1] = f2bf(v.y); o[2] = f2bf(v.z); o[3] = f2bf(v.w);
    *(u16x4*)(out + i) = o;
}

// ---------------- concat 3 bias vectors into [3072] ----------------
__global__ void concat_bias(const float* __restrict__ qb, const float* __restrict__ kb,
                            const float* __restrict__ vb, float* __restrict__ o) {
    int i = blockIdx.x * blockDim.x + threadIdx.x;
    if (i < DDIM) o[i] = qb[i];
    else if (i < DDIM + NKV) o[i] = kb[i - DDIM];
    else if (i < NQKV) o[i] = vb[i - DDIM - NKV];
}

// ---------------- RoPE in-place on bf16 buffer ----------------
__global__ void rope_bf16(unsigned short* __restrict__ buf,
                          const float* __restrict__ cosT,
                          const float* __restrict__ sinT,
                          int pitch, int col0, int nhalf, float oscale) {
    int r = blockIdx.x;             // 0..MROWS-1
    int pos = r & (SDIM - 1);
    unsigned short* row = buf + (size_t)r * pitch + col0;
    for (int p = threadIdx.x; p < nhalf; p += blockDim.x) {
        int hh = p >> 6, i = p & 63;
        int base = hh * 128 + i * 2;
        float xr = bf2f(row[base]), xi = bf2f(row[base + 1]);
        float c = cosT[pos * 64 + i], s = sinT[pos * 64 + i];
        row[base]     = f2bf((xr * c - xi * s) * oscale);
        row[base + 1] = f2bf((xr * s + xi * c) * oscale);
    }
}

// ---------------- transpose V: qkv cols [2560,3072) -> Vt[b*512+gd][2048] ----------------
__global__ void transpose_v(const unsigned short* __restrict__ qkv,
                            unsigned short* __restrict__ Vt) {
    __shared__ unsigned short T[32][33];
    int s0 = blockIdx.x * 32, d0 = blockIdx.y * 32, b = blockIdx.z;
    int c = threadIdx.x & 31, r4 = threadIdx.x >> 5;   // 8 row-groups
    for (int rr = r4; rr < 32; rr += 8)
        T[rr][c] = qkv[(size_t)(b * SDIM + s0 + rr) * NQKV + (DDIM + NKV) + d0 + c];
    __syncthreads();
    for (int rr = r4; rr < 32; rr += 8)
        Vt[(size_t)(b * NKV + d0 + rr) * SDIM + s0 + c] = T[c][rr];
}

// ---------------- GEMM: C[M,N] = A[M,K] * B[N,K]^T + bias (m97 recipe) ----------------
template <int BF16OUT>
__global__ __launch_bounds__(256) void gemm_bt(
    const unsigned short* __restrict__ A,
    const unsigned short* __restrict__ Bm,
    const float* __restrict__ bias,
    void* __restrict__ Cv,
    int Ndim, int Kdim) {
    __shared__ unsigned short As[128 * 32];
    __shared__ unsigned short Bs[128 * 32];
    const int tid = threadIdx.x;
    const int w = tid >> 6, lane = tid & 63;
    const int ml = lane & 15, quad = lane >> 4;
    const int m0 = blockIdx.y * 128, n0 = blockIdx.x * 128;
    const int wr = (w >> 1) * 64, wc = (w & 1) * 64;

    f32x4 acc[4][4] = {};

    const int c0 = tid, c1 = tid + 256;
    const int ar0 = c0 >> 2, ak0 = (c0 & 3) * 8;
    const int ar1 = c1 >> 2, ak1 = (c1 & 3) * 8;

    for (int kt = 0; kt < Kdim; kt += 32) {
        __builtin_amdgcn_global_load_lds(
            (const AS1 unsigned int*)(A + (size_t)(m0 + ar0) * Kdim + kt + ak0),
            (AS3 unsigned int*)(As + c0 * 8), 16, 0, 0);
        __builtin_amdgcn_global_load_lds(
            (const AS1 unsigned int*)(A + (size_t)(m0 + ar1) * Kdim + kt + ak1),
            (AS3 unsigned int*)(As + c1 * 8), 16, 0, 0);
        __builtin_amdgcn_global_load_lds(
            (const AS1 unsigned int*)(Bm + (size_t)(n0 + ar0) * Kdim + kt + ak0),
            (AS3 unsigned int*)(Bs + c0 * 8), 16, 0, 0);
        __builtin_amdgcn_global_load_lds(
            (const AS1 unsigned int*)(Bm + (size_t)(n0 + ar1) * Kdim + kt + ak1),
            (AS3 unsigned int*)(Bs + c1 * 8), 16, 0, 0);
        __syncthreads();

        bf16x8 af[4], bfr[4];
#pragma unroll
        for (int i = 0; i < 4; ++i)
            af[i] = *(const bf16x8*)&As[(wr + i * 16 + ml) * 32 + quad * 8];
#pragma unroll
        for (int j = 0; j < 4; ++j)
            bfr[j] = *(const bf16x8*)&Bs[(wc + j * 16 + ml) * 32 + quad * 8];
#pragma unroll
        for (int i = 0; i < 4; ++i)
#pragma unroll
            for (int j = 0; j < 4; ++j)
                acc[i][j] = __builtin_amdgcn_mfma_f32_16x16x32_bf16(af[i], bfr[j], acc[i][j], 0, 0, 0);
        __syncthreads();
    }

#pragma unroll
    for (int j = 0; j < 4; ++j) {
        int col = n0 + wc + j * 16 + ml;
        float bj = bias[col];
#pragma unroll
        for (int i = 0; i < 4; ++i) {
            int row0 = m0 + wr + i * 16 + quad * 4;
#pragma unroll
            for (int r = 0; r < 4; ++r) {
                float v = acc[i][j][r] + bj;
                if (BF16OUT)
                    ((unsigned short*)Cv)[(size_t)(row0 + r) * Ndim + col] = f2bf(v);
                else
                    ((float*)Cv)[(size_t)(row0 + r) * Ndim + col] = v;
            }
        }
    }
}

// ---------------- Flash attention (causal, GQA), bf16 in/out ----------------
// Qp: qkv cols [0,2048), pitch 3072 (scale pre-folded). Kp: qkv cols [2048,2560), pitch 3072.
// Vt: [B*NKV][SDIM] pre-transposed. O: [MROWS][DDIM] bf16.
__global__ __launch_bounds__(256, 3) void attn_fwd(
    const unsigned short* __restrict__ Qp,
    const unsigned short* __restrict__ Kp,
    const unsigned short* __restrict__ Vt,
    unsigned short* __restrict__ O) {
    const int qt = blockIdx.x;  // q tile (64 rows)
    const int h  = blockIdx.y;
    const int b  = blockIdx.z;
    const int g  = h >> 2;
    const int tid = threadIdx.x;
    const int w = tid >> 6, lane = tid & 63;
    const int ml = lane & 15, quad = lane >> 4;
    const int seg = lane & 3, rsub = lane >> 2;

    __shared__ unsigned short Ks[4 * 64 * 32];   // [kc][row][32] chunked
    __shared__ unsigned short Vs[2 * 128 * 32];  // [kc2][d][32] chunked
    __shared__ unsigned short Ps[4 * 16 * 72];   // per-wave P, pitch 72

    // Q A-fragments, loaded once (wave w owns q rows w*16..w*16+15)
    bf16x8 aq[4];
    const size_t qgrow = (size_t)(b * SDIM + qt * 64 + w * 16 + ml);
#pragma unroll
    for (int kc = 0; kc < 4; ++kc)
        aq[kc] = *(const bf16x8*)(Qp + qgrow * NQKV + h * DKH + kc * 32 + quad * 8);

    f32x4 o_acc[8] = {};
    float m_run[4], l_run[4];
#pragma unroll
    for (int r = 0; r < 4; ++r) { m_run[r] = -INFINITY; l_run[r] = 0.f; }

    const int q_base = qt * 64 + w * 16 + quad * 4;
    unsigned short* Pw = Ps + w * 16 * 72;

    for (int kt = 0; kt <= qt; ++kt) {
        const int kb = kt * 64;
        __syncthreads();  // previous tile fully consumed
        // stage K tile (64x128) chunked: wave w loads rows w*16..+15 of each kc chunk
#pragma unroll
        for (int kc = 0; kc < 4; ++kc)
            __builtin_amdgcn_global_load_lds(
                (const AS1 unsigned int*)(Kp + (size_t)(b * SDIM + kb + w * 16 + rsub) * NQKV + g * DKH + kc * 32 + seg * 8),
                (AS3 unsigned int*)(Ks + kc * 2048 + w * 512 + lane * 8), 16, 0, 0);
        // stage V^T tile (128 d x 64 s) chunked: 16 units of 16 d-rows
#pragma unroll
        for (int c = 0; c < 4; ++c) {
            int u = w * 4 + c, kc2 = u >> 3, rg = u & 7;
            __builtin_amdgcn_global_load_lds(
                (const AS1 unsigned int*)(Vt + (size_t)(b * NKV + g * DKH + rg * 16 + rsub) * SDIM + kb + kc2 * 32 + seg * 8),
                (AS3 unsigned int*)(Vs + u * 512 + lane * 8), 16, 0, 0);
        }
        __syncthreads();

        // QK^T: 16 q rows x 64 k cols per wave
        f32x4 s[4];
#pragma unroll
        for (int nt = 0; nt < 4; ++nt) {
            f32x4 sc = {};
#pragma unroll
            for (int kc = 0; kc < 4; ++kc) {
                bf16x8 bk = *(const bf16x8*)&Ks[kc * 2048 + (nt * 16 + ml) * 32 + quad * 8];
                sc = __builtin_amdgcn_mfma_f32_16x16x32_bf16(aq[kc], bk, sc, 0, 0, 0);
            }
            s[nt] = sc;
        }

        float mx[4] = {-INFINITY, -INFINITY, -INFINITY, -INFINITY};
        if (kt == qt) {  // diagonal tile: apply causal mask
#pragma unroll
            for (int nt = 0; nt < 4; ++nt) {
                int kcol = kb + nt * 16 + ml;
#pragma unroll
                for (int r = 0; r < 4; ++r) {
                    float x = s[nt][r];
                    if (kcol > q_base + r) x = -INFINITY;
                    s[nt][r] = x;
                    mx[r] = fmaxf(mx[r], x);
                }
            }
        } else {
#pragma unroll
            for (int nt = 0; nt < 4; ++nt)
#pragma unroll
                for (int r = 0; r < 4; ++r)
                    mx[r] = fmaxf(mx[r], s[nt][r]);
        }
#pragma unroll
        for (int r = 0; r < 4; ++r) {
            mx[r] = fmaxf(mx[r], __shfl_xor(mx[r], 1));
            mx[r] = fmaxf(mx[r], __shfl_xor(mx[r], 2));
            mx[r] = fmaxf(mx[r], __shfl_xor(mx[r], 4));
            mx[r] = fmaxf(mx[r], __shfl_xor(mx[r], 8));
        }

        float m_new[4], alpha[4], lad[4];
#pragma unroll
        for (int r = 0; r < 4; ++r) {
            m_new[r] = fmaxf(m_run[r], mx[r]);
            alpha[r] = __expf(m_run[r] - m_new[r]);
            lad[r] = 0.f;
        }
#pragma unroll
        for (int nt = 0; nt < 4; ++nt)
#pragma unroll
            for (int r = 0; r < 4; ++r) {
                float p = __expf(s[nt][r] - m_new[r]);
                lad[r] += p;
                Pw[(quad * 4 + r) * 72 + nt * 16 + ml] = f2bf(p);
            }
#pragma unroll
        for (int r = 0; r < 4; ++r) {
            lad[r] += __shfl_xor(lad[r], 1);
            lad[r] += __shfl_xor(lad[r], 2);
            lad[r] += __shfl_xor(lad[r], 4);
            lad[r] += __shfl_xor(lad[r], 8);
            l_run[r] = l_run[r] * alpha[r] + lad[r];
            m_run[r] = m_new[r];
        }
#pragma unroll
        for (int dt = 0; dt < 8; ++dt)
#pragma unroll
            for (int r = 0; r < 4; ++r)
                o_acc[dt][r] *= alpha[r];

        // PV: P(16x64) x V(64x128) — P A-frags via per-wave LDS round-trip
        bf16x8 ap0 = *(const bf16x8*)&Pw[ml * 72 + quad * 8];
        bf16x8 ap1 = *(const bf16x8*)&Pw[ml * 72 + 32 + quad * 8];
#pragma unroll
        for (int dt = 0; dt < 8; ++dt) {
            bf16x8 b0 = *(const bf16x8*)&Vs[(dt * 16 + ml) * 32 + quad * 8];
            bf16x8 b1 = *(const bf16x8*)&Vs[4096 + (dt * 16 + ml) * 32 + quad * 8];
            o_acc[dt] = __builtin_amdgcn_mfma_f32_16x16x32_bf16(ap0, b0, o_acc[dt], 0, 0, 0);
            o_acc[dt] = __builtin_amdgcn_mfma_f32_16x16x32_bf16(ap1, b1, o_acc[dt], 0, 0, 0);
        }
    }

    // epilogue
#pragma unroll
    for (int dt = 0; dt < 8; ++dt)
#pragma unroll
        for (int r = 0; r < 4; ++r) {
            float ov = o_acc[dt][r] / l_run[r];
            O[(size_t)(b * SDIM + q_base + r) * DDIM + h * DKH + dt * 16 + ml] = f2bf(ov);
        }
}

// ---------------- host launch ----------------
extern "C" void kernel_launch(void* const* d_in, const int* in_sizes, int n_in,
                              void* d_out, int out_size, void* d_ws, size_t ws_size,
                              hipStream_t stream) {
    const float* x    = (const float*)d_in[0];
    const float* fcos = (const float*)d_in[1];
    const float* fsin = (const float*)d_in[2];
    const float* wq_w = (const float*)d_in[3];
    const float* wq_b = (const float*)d_in[4];
    const float* wk_w = (const float*)d_in[5];
    const float* wk_b = (const float*)d_in[6];
    const float* wv_w = (const float*)d_in[7];
    const float* wv_b = (const float*)d_in[8];
    const float* wo_w = (const float*)d_in[9];
    const float* wo_b = (const float*)d_in[10];
    float* out = (float*)d_out;

    char* ws = (char*)d_ws;
    size_t off = 0;
    auto alloc = [&](size_t bytes) {
        char* p = ws + off;
        off += (bytes + 255) & ~(size_t)255;
        return p;
    };
    unsigned short* xb  = (unsigned short*)alloc((size_t)MROWS * DDIM * 2);
    unsigned short* W3  = (unsigned short*)alloc((size_t)NQKV * DDIM * 2);  // wq|wk|wv rows
    unsigned short* wob = (unsigned short*)alloc((size_t)DDIM * DDIM * 2);
    float* b3           = (float*)alloc((size_t)NQKV * 4);
    unsigned short* qkv = (unsigned short*)alloc((size_t)MROWS * NQKV * 2);
    unsigned short* Vt  = (unsigned short*)alloc((size_t)BDIM * NKV * SDIM * 2);
    unsigned short* att = (unsigned short*)alloc((size_t)MROWS * DDIM * 2);

    auto cast_launch = [&](const float* in, unsigned short* o, int n) {
        int blocks = (n / 4 + 255) / 256;
        cast_f32_to_bf16<<<dim3(blocks), dim3(256), 0, stream>>>(in, o, n);
    };
    cast_launch(x,    xb, MROWS * DDIM);
    cast_launch(wq_w, W3,                      DDIM * DDIM);
    cast_launch(wk_w, W3 + (size_t)DDIM * DDIM,        NKV * DDIM);
    cast_launch(wv_w, W3 + (size_t)(DDIM + NKV) * DDIM, NKV * DDIM);
    cast_launch(wo_w, wob, DDIM * DDIM);
    concat_bias<<<dim3(12), dim3(256), 0, stream>>>(wq_b, wk_b, wv_b, b3);

    // fused QKV projection: [4096,3072] bf16
    gemm_bt<1><<<dim3(NQKV / 128, MROWS / 128), 256, 0, stream>>>(xb, W3, b3, qkv, NQKV, DDIM);

    const float scale = 0.08838834764831845f;  // 1/sqrt(128), folded into Q
    rope_bf16<<<dim3(MROWS), dim3(256), 0, stream>>>(qkv, fcos, fsin, NQKV, 0,    1024, scale);
    rope_bf16<<<dim3(MROWS), dim3(256), 0, stream>>>(qkv, fcos, fsin, NQKV, DDIM, 256,  1.0f);
    transpose_v<<<dim3(SDIM / 32, NKV / 32, BDIM), 256, 0, stream>>>(qkv, Vt);

    attn_fwd<<<dim3(SDIM / 64, HQ, BDIM), 256, 0, stream>>>(qkv, qkv + DDIM, Vt, att);

    // output projection (f32 out)
    gemm_bt<0><<<dim3(DDIM / 128, MROWS / 128), 256, 0, stream>>>(att, wob, wo_b, out, DDIM, DDIM);
}

// Round 3
// 374.197 us; speedup vs baseline: 2.1200x; 1.1511x over previous
//
#include <hip/hip_runtime.h>

#define BDIM 2
#define SDIM 2048
#define DDIM 2048
#define HQ 16
#define HKV 4
#define DKH 128
#define NKV 512      // HKV*DKH
#define NQKV 3072    // DDIM + 2*NKV
#define MROWS 4096   // B*S

typedef __attribute__((ext_vector_type(8))) short bf16x8;
typedef __attribute__((ext_vector_type(4))) float f32x4;
typedef __attribute__((ext_vector_type(8))) unsigned short u16x8;
typedef __attribute__((ext_vector_type(4))) unsigned short u16x4;

#define AS1 __attribute__((address_space(1)))
#define AS3 __attribute__((address_space(3)))

__device__ __forceinline__ unsigned short f2bf(float f) {
    union { float f; unsigned int u; } v; v.f = f;
    unsigned int r = v.u + 0x7FFFu + ((v.u >> 16) & 1u);
    return (unsigned short)(r >> 16);
}
__device__ __forceinline__ float bf2f(unsigned short u) {
    union { unsigned int u; float f; } v; v.u = ((unsigned int)u) << 16;
    return v.f;
}

// ---------------- cast f32 -> bf16 ----------------
__global__ void cast_f32_to_bf16(const float* __restrict__ in,
                                 unsigned short* __restrict__ out, int n) {
    int i = (blockIdx.x * blockDim.x + threadIdx.x) * 4;
    if (i >= n) return;
    float4 v = *(const float4*)(in + i);
    u16x4 o;
    o[0] = f2bf(v.x); o[1] = f2bf(v.y); o[2] = f2bf(v.z); o[3] = f2bf(v.w);
    *(u16x4*)(out + i) = o;
}

// ---------------- concat 3 bias vectors into [3072] ----------------
__global__ void concat_bias(const float* __restrict__ qb, const float* __restrict__ kb,
                            const float* __restrict__ vb, float* __restrict__ o) {
    int i = blockIdx.x * blockDim.x + threadIdx.x;
    if (i < DDIM) o[i] = qb[i];
    else if (i < DDIM + NKV) o[i] = kb[i - DDIM];
    else if (i < NQKV) o[i] = vb[i - DDIM - NKV];
}

// ---------------- RoPE in-place on bf16 buffer ----------------
__global__ void rope_bf16(unsigned short* __restrict__ buf,
                          const float* __restrict__ cosT,
                          const float* __restrict__ sinT,
                          int pitch, int col0, int nhalf, float oscale) {
    int r = blockIdx.x;             // 0..MROWS-1
    int pos = r & (SDIM - 1);
    unsigned short* row = buf + (size_t)r * pitch + col0;
    for (int p = threadIdx.x; p < nhalf; p += blockDim.x) {
        int hh = p >> 6, i = p & 63;
        int base = hh * 128 + i * 2;
        float xr = bf2f(row[base]), xi = bf2f(row[base + 1]);
        float c = cosT[pos * 64 + i], s = sinT[pos * 64 + i];
        row[base]     = f2bf((xr * c - xi * s) * oscale);
        row[base + 1] = f2bf((xr * s + xi * c) * oscale);
    }
}

// ---------------- transpose V: qkv cols [2560,3072) -> Vt[b*512+gd][2048] ----------------
__global__ void transpose_v(const unsigned short* __restrict__ qkv,
                            unsigned short* __restrict__ Vt) {
    __shared__ unsigned short T[32][33];
    int s0 = blockIdx.x * 32, d0 = blockIdx.y * 32, b = blockIdx.z;
    int c = threadIdx.x & 31, r4 = threadIdx.x >> 5;   // 8 row-groups
    for (int rr = r4; rr < 32; rr += 8)
        T[rr][c] = qkv[(size_t)(b * SDIM + s0 + rr) * NQKV + (DDIM + NKV) + d0 + c];
    __syncthreads();
    for (int rr = r4; rr < 32; rr += 8)
        Vt[(size_t)(b * NKV + d0 + rr) * SDIM + s0 + c] = T[c][rr];
}

// ---------------- GEMM: C[M,N] = A[M,K] * B[N,K]^T + bias (m97 recipe) ----------------
template <int BF16OUT>
__global__ __launch_bounds__(256) void gemm_bt(
    const unsigned short* __restrict__ A,
    const unsigned short* __restrict__ Bm,
    const float* __restrict__ bias,
    void* __restrict__ Cv,
    int Ndim, int Kdim) {
    __shared__ unsigned short As[128 * 32];
    __shared__ unsigned short Bs[128 * 32];
    const int tid = threadIdx.x;
    const int w = tid >> 6, lane = tid & 63;
    const int ml = lane & 15, quad = lane >> 4;
    const int m0 = blockIdx.y * 128, n0 = blockIdx.x * 128;
    const int wr = (w >> 1) * 64, wc = (w & 1) * 64;

    f32x4 acc[4][4] = {};

    const int c0 = tid, c1 = tid + 256;
    const int ar0 = c0 >> 2, ak0 = (c0 & 3) * 8;
    const int ar1 = c1 >> 2, ak1 = (c1 & 3) * 8;

    for (int kt = 0; kt < Kdim; kt += 32) {
        __builtin_amdgcn_global_load_lds(
            (const AS1 unsigned int*)(A + (size_t)(m0 + ar0) * Kdim + kt + ak0),
            (AS3 unsigned int*)(As + c0 * 8), 16, 0, 0);
        __builtin_amdgcn_global_load_lds(
            (const AS1 unsigned int*)(A + (size_t)(m0 + ar1) * Kdim + kt + ak1),
            (AS3 unsigned int*)(As + c1 * 8), 16, 0, 0);
        __builtin_amdgcn_global_load_lds(
            (const AS1 unsigned int*)(Bm + (size_t)(n0 + ar0) * Kdim + kt + ak0),
            (AS3 unsigned int*)(Bs + c0 * 8), 16, 0, 0);
        __builtin_amdgcn_global_load_lds(
            (const AS1 unsigned int*)(Bm + (size_t)(n0 + ar1) * Kdim + kt + ak1),
            (AS3 unsigned int*)(Bs + c1 * 8), 16, 0, 0);
        __syncthreads();

        bf16x8 af[4], bfr[4];
#pragma unroll
        for (int i = 0; i < 4; ++i)
            af[i] = *(const bf16x8*)&As[(wr + i * 16 + ml) * 32 + quad * 8];
#pragma unroll
        for (int j = 0; j < 4; ++j)
            bfr[j] = *(const bf16x8*)&Bs[(wc + j * 16 + ml) * 32 + quad * 8];
#pragma unroll
        for (int i = 0; i < 4; ++i)
#pragma unroll
            for (int j = 0; j < 4; ++j)
                acc[i][j] = __builtin_amdgcn_mfma_f32_16x16x32_bf16(af[i], bfr[j], acc[i][j], 0, 0, 0);
        __syncthreads();
    }

#pragma unroll
    for (int j = 0; j < 4; ++j) {
        int col = n0 + wc + j * 16 + ml;
        float bj = bias[col];
#pragma unroll
        for (int i = 0; i < 4; ++i) {
            int row0 = m0 + wr + i * 16 + quad * 4;
#pragma unroll
            for (int r = 0; r < 4; ++r) {
                float v = acc[i][j][r] + bj;
                if (BF16OUT)
                    ((unsigned short*)Cv)[(size_t)(row0 + r) * Ndim + col] = f2bf(v);
                else
                    ((float*)Cv)[(size_t)(row0 + r) * Ndim + col] = v;
            }
        }
    }
}

// ---------------- Flash attention (causal, GQA), bf16 in/out ----------------
// Q tile 128 rows/block, 32 rows/wave (2 groups of 16). KV tile 64.
// Qp: qkv cols [0,2048), pitch 3072 (scale pre-folded). Kp: qkv cols [2048,2560).
// Vt: [B*NKV][SDIM] pre-transposed. O: [MROWS][DDIM] bf16.
__global__ __launch_bounds__(256, 2) void attn_fwd(
    const unsigned short* __restrict__ Qp,
    const unsigned short* __restrict__ Kp,
    const unsigned short* __restrict__ Vt,
    unsigned short* __restrict__ O) {
    const int l  = blockIdx.x;
    const int qt = 15 - (l >> 5);   // heaviest q-tiles dispatch first
    const int h  = l & 15;
    const int b  = (l >> 4) & 1;
    const int g  = h >> 2;
    const int tid = threadIdx.x;
    const int w = tid >> 6, lane = tid & 63;
    const int ml = lane & 15, quad = lane >> 4;
    const int seg = lane & 3, rsub = lane >> 2;

    __shared__ unsigned short Ks[4 * 64 * 32];   // [kc][krow][32] chunked
    __shared__ unsigned short Vs[2 * 128 * 32];  // [kc2][d][32] chunked
    __shared__ unsigned short Ps[4 * 32 * 72];   // per-wave P (32 rows, pitch 72)

    // Q A-fragments: wave w owns rows qt*128 + w*32 + g2*16 + ml
    bf16x8 aq[2][4];
#pragma unroll
    for (int g2 = 0; g2 < 2; ++g2) {
        const size_t qrow = (size_t)(b * SDIM + qt * 128 + w * 32 + g2 * 16 + ml);
#pragma unroll
        for (int kc = 0; kc < 4; ++kc)
            aq[g2][kc] = *(const bf16x8*)(Qp + qrow * NQKV + h * DKH + kc * 32 + quad * 8);
    }

    f32x4 o_acc[2][8] = {};
    float m_run[2][4], l_run[2][4];
#pragma unroll
    for (int g2 = 0; g2 < 2; ++g2)
#pragma unroll
        for (int r = 0; r < 4; ++r) { m_run[g2][r] = -INFINITY; l_run[g2][r] = 0.f; }

    const int q0 = qt * 128 + w * 32;            // wave's first q row
    unsigned short* Pw = Ps + w * 32 * 72;
    const int ktend = 2 * qt + 2;

    for (int kt = 0; kt < ktend; ++kt) {
        const int kb = kt * 64;
        __syncthreads();  // previous tile fully consumed
        // stage K tile (64 x 128) chunked
#pragma unroll
        for (int kc = 0; kc < 4; ++kc)
            __builtin_amdgcn_global_load_lds(
                (const AS1 unsigned int*)(Kp + (size_t)(b * SDIM + kb + w * 16 + rsub) * NQKV + g * DKH + kc * 32 + seg * 8),
                (AS3 unsigned int*)(Ks + kc * 2048 + w * 512 + lane * 8), 16, 0, 0);
        // stage V^T tile (128 d x 64 s) chunked
#pragma unroll
        for (int c = 0; c < 4; ++c) {
            int u = w * 4 + c, kc2 = u >> 3, rg = u & 7;
            __builtin_amdgcn_global_load_lds(
                (const AS1 unsigned int*)(Vt + (size_t)(b * NKV + g * DKH + rg * 16 + rsub) * SDIM + kb + kc2 * 32 + seg * 8),
                (AS3 unsigned int*)(Vs + u * 512 + lane * 8), 16, 0, 0);
        }
        __syncthreads();

        const bool active = (kb <= q0 + 31);   // wave fully above diagonal -> skip compute
        if (active) {
            // QK^T: 32 q rows x 64 k cols per wave; each bk frag feeds 2 MFMAs
            f32x4 s[2][4];
#pragma unroll
            for (int nt = 0; nt < 4; ++nt) {
                bf16x8 bk[4];
#pragma unroll
                for (int kc = 0; kc < 4; ++kc)
                    bk[kc] = *(const bf16x8*)&Ks[kc * 2048 + (nt * 16 + ml) * 32 + quad * 8];
#pragma unroll
                for (int g2 = 0; g2 < 2; ++g2) {
                    f32x4 sc = {};
#pragma unroll
                    for (int kc = 0; kc < 4; ++kc)
                        sc = __builtin_amdgcn_mfma_f32_16x16x32_bf16(aq[g2][kc], bk[kc], sc, 0, 0, 0);
                    s[g2][nt] = sc;
                }
            }

            const bool diag = (kb + 63 > q0);
            float mx[2][4];
#pragma unroll
            for (int g2 = 0; g2 < 2; ++g2)
#pragma unroll
                for (int r = 0; r < 4; ++r) mx[g2][r] = -INFINITY;
            if (diag) {
#pragma unroll
                for (int g2 = 0; g2 < 2; ++g2) {
                    int rb = q0 + g2 * 16 + quad * 4;
#pragma unroll
                    for (int nt = 0; nt < 4; ++nt) {
                        int kcol = kb + nt * 16 + ml;
#pragma unroll
                        for (int r = 0; r < 4; ++r) {
                            float x = s[g2][nt][r];
                            if (kcol > rb + r) x = -INFINITY;
                            s[g2][nt][r] = x;
                            mx[g2][r] = fmaxf(mx[g2][r], x);
                        }
                    }
                }
            } else {
#pragma unroll
                for (int g2 = 0; g2 < 2; ++g2)
#pragma unroll
                    for (int nt = 0; nt < 4; ++nt)
#pragma unroll
                        for (int r = 0; r < 4; ++r)
                            mx[g2][r] = fmaxf(mx[g2][r], s[g2][nt][r]);
            }

#pragma unroll
            for (int g2 = 0; g2 < 2; ++g2) {
#pragma unroll
                for (int r = 0; r < 4; ++r) {
                    float m = mx[g2][r];
                    m = fmaxf(m, __shfl_xor(m, 1));
                    m = fmaxf(m, __shfl_xor(m, 2));
                    m = fmaxf(m, __shfl_xor(m, 4));
                    m = fmaxf(m, __shfl_xor(m, 8));
                    mx[g2][r] = m;
                }
            }

            float alpha[2][4];
#pragma unroll
            for (int g2 = 0; g2 < 2; ++g2) {
                float lad[4];
#pragma unroll
                for (int r = 0; r < 4; ++r) {
                    float m_new = fmaxf(m_run[g2][r], mx[g2][r]);
                    alpha[g2][r] = __expf(m_run[g2][r] - m_new);
                    m_run[g2][r] = m_new;
                    lad[r] = 0.f;
                }
#pragma unroll
                for (int nt = 0; nt < 4; ++nt)
#pragma unroll
                    for (int r = 0; r < 4; ++r) {
                        float p = __expf(s[g2][nt][r] - m_run[g2][r]);
                        lad[r] += p;
                        Pw[(g2 * 16 + quad * 4 + r) * 72 + nt * 16 + ml] = f2bf(p);
                    }
#pragma unroll
                for (int r = 0; r < 4; ++r) {
                    lad[r] += __shfl_xor(lad[r], 1);
                    lad[r] += __shfl_xor(lad[r], 2);
                    lad[r] += __shfl_xor(lad[r], 4);
                    lad[r] += __shfl_xor(lad[r], 8);
                    l_run[g2][r] = l_run[g2][r] * alpha[g2][r] + lad[r];
                }
            }
#pragma unroll
            for (int g2 = 0; g2 < 2; ++g2)
#pragma unroll
                for (int dt = 0; dt < 8; ++dt)
#pragma unroll
                    for (int r = 0; r < 4; ++r)
                        o_acc[g2][dt][r] *= alpha[g2][r];

            // PV: each bv frag feeds 2 MFMAs (both row groups)
            bf16x8 ap[2][2];
#pragma unroll
            for (int g2 = 0; g2 < 2; ++g2) {
                ap[g2][0] = *(const bf16x8*)&Pw[(g2 * 16 + ml) * 72 + quad * 8];
                ap[g2][1] = *(const bf16x8*)&Pw[(g2 * 16 + ml) * 72 + 32 + quad * 8];
            }
#pragma unroll
            for (int dt = 0; dt < 8; ++dt) {
                bf16x8 b0 = *(const bf16x8*)&Vs[(dt * 16 + ml) * 32 + quad * 8];
                bf16x8 b1 = *(const bf16x8*)&Vs[4096 + (dt * 16 + ml) * 32 + quad * 8];
#pragma unroll
                for (int g2 = 0; g2 < 2; ++g2) {
                    o_acc[g2][dt] = __builtin_amdgcn_mfma_f32_16x16x32_bf16(ap[g2][0], b0, o_acc[g2][dt], 0, 0, 0);
                    o_acc[g2][dt] = __builtin_amdgcn_mfma_f32_16x16x32_bf16(ap[g2][1], b1, o_acc[g2][dt], 0, 0, 0);
                }
            }
        }
    }

    // epilogue
#pragma unroll
    for (int g2 = 0; g2 < 2; ++g2)
#pragma unroll
        for (int dt = 0; dt < 8; ++dt)
#pragma unroll
            for (int r = 0; r < 4; ++r) {
                float ov = o_acc[g2][dt][r] / l_run[g2][r];
                O[(size_t)(b * SDIM + q0 + g2 * 16 + quad * 4 + r) * DDIM + h * DKH + dt * 16 + ml] = f2bf(ov);
            }
}

// ---------------- host launch ----------------
extern "C" void kernel_launch(void* const* d_in, const int* in_sizes, int n_in,
                              void* d_out, int out_size, void* d_ws, size_t ws_size,
                              hipStream_t stream) {
    const float* x    = (const float*)d_in[0];
    const float* fcos = (const float*)d_in[1];
    const float* fsin = (const float*)d_in[2];
    const float* wq_w = (const float*)d_in[3];
    const float* wq_b = (const float*)d_in[4];
    const float* wk_w = (const float*)d_in[5];
    const float* wk_b = (const float*)d_in[6];
    const float* wv_w = (const float*)d_in[7];
    const float* wv_b = (const float*)d_in[8];
    const float* wo_w = (const float*)d_in[9];
    const float* wo_b = (const float*)d_in[10];
    float* out = (float*)d_out;

    char* ws = (char*)d_ws;
    size_t off = 0;
    auto alloc = [&](size_t bytes) {
        char* p = ws + off;
        off += (bytes + 255) & ~(size_t)255;
        return p;
    };
    unsigned short* xb  = (unsigned short*)alloc((size_t)MROWS * DDIM * 2);
    unsigned short* W3  = (unsigned short*)alloc((size_t)NQKV * DDIM * 2);  // wq|wk|wv rows
    unsigned short* wob = (unsigned short*)alloc((size_t)DDIM * DDIM * 2);
    float* b3           = (float*)alloc((size_t)NQKV * 4);
    unsigned short* qkv = (unsigned short*)alloc((size_t)MROWS * NQKV * 2);
    unsigned short* Vt  = (unsigned short*)alloc((size_t)BDIM * NKV * SDIM * 2);
    unsigned short* att = (unsigned short*)alloc((size_t)MROWS * DDIM * 2);

    auto cast_launch = [&](const float* in, unsigned short* o, int n) {
        int blocks = (n / 4 + 255) / 256;
        cast_f32_to_bf16<<<dim3(blocks), dim3(256), 0, stream>>>(in, o, n);
    };
    cast_launch(x,    xb, MROWS * DDIM);
    cast_launch(wq_w, W3,                      DDIM * DDIM);
    cast_launch(wk_w, W3 + (size_t)DDIM * DDIM,        NKV * DDIM);
    cast_launch(wv_w, W3 + (size_t)(DDIM + NKV) * DDIM, NKV * DDIM);
    cast_launch(wo_w, wob, DDIM * DDIM);
    concat_bias<<<dim3(12), dim3(256), 0, stream>>>(wq_b, wk_b, wv_b, b3);

    // fused QKV projection: [4096,3072] bf16
    gemm_bt<1><<<dim3(NQKV / 128, MROWS / 128), 256, 0, stream>>>(xb, W3, b3, qkv, NQKV, DDIM);

    const float scale = 0.08838834764831845f;  // 1/sqrt(128), folded into Q
    rope_bf16<<<dim3(MROWS), dim3(256), 0, stream>>>(qkv, fcos, fsin, NQKV, 0,    1024, scale);
    rope_bf16<<<dim3(MROWS), dim3(256), 0, stream>>>(qkv, fcos, fsin, NQKV, DDIM, 256,  1.0f);
    transpose_v<<<dim3(SDIM / 32, NKV / 32, BDIM), 256, 0, stream>>>(qkv, Vt);

    attn_fwd<<<dim3(512), dim3(256), 0, stream>>>(qkv, qkv + DDIM, Vt, att);

    // output projection (f32 out)
    gemm_bt<0><<<dim3(DDIM / 128, MROWS / 128), 256, 0, stream>>>(att, wob, wo_b, out, DDIM, DDIM);
}

// Round 4
// 334.441 us; speedup vs baseline: 2.3720x; 1.1189x over previous
//
#include <hip/hip_runtime.h>

#define BDIM 2
#define SDIM 2048
#define DDIM 2048
#define HQ 16
#define HKV 4
#define DKH 128
#define NKV 512      // HKV*DKH
#define NQKV 3072    // DDIM + 2*NKV
#define MROWS 4096   // B*S

typedef __attribute__((ext_vector_type(8))) short bf16x8;
typedef __attribute__((ext_vector_type(4))) float f32x4;
typedef __attribute__((ext_vector_type(8))) unsigned short u16x8;
typedef __attribute__((ext_vector_type(4))) unsigned short u16x4;

#define AS1 __attribute__((address_space(1)))
#define AS3 __attribute__((address_space(3)))

__device__ __forceinline__ unsigned short f2bf(float f) {
    union { float f; unsigned int u; } v; v.f = f;
    unsigned int r = v.u + 0x7FFFu + ((v.u >> 16) & 1u);
    return (unsigned short)(r >> 16);
}
__device__ __forceinline__ float bf2f(unsigned short u) {
    union { unsigned int u; float f; } v; v.u = ((unsigned int)u) << 16;
    return v.f;
}
__device__ __forceinline__ unsigned int pack2bf(float a, float b) {
    return (unsigned int)f2bf(a) | ((unsigned int)f2bf(b) << 16);
}

// ---------------- fused cast f32 -> bf16 for x|wq|wk|wv|wo (contiguous dst) ----------------
#define NX   ((size_t)MROWS * DDIM)            // 8388608
#define NWQ  ((size_t)DDIM * DDIM)             // 4194304
#define NWKV ((size_t)NKV * DDIM)              // 1048576
__global__ void cast_all(const float* __restrict__ x, const float* __restrict__ wq,
                         const float* __restrict__ wk, const float* __restrict__ wv,
                         const float* __restrict__ wo, unsigned short* __restrict__ dst) {
    size_t i = ((size_t)blockIdx.x * blockDim.x + threadIdx.x) * 4;
    const size_t N0 = NX, N1 = N0 + NWQ, N2 = N1 + NWKV, N3 = N2 + NWKV, N4 = N3 + NWQ;
    if (i >= N4) return;
    const float* src; size_t off;
    if (i < N0)      { src = x;  off = i; }
    else if (i < N1) { src = wq; off = i - N0; }
    else if (i < N2) { src = wk; off = i - N1; }
    else if (i < N3) { src = wv; off = i - N2; }
    else             { src = wo; off = i - N3; }
    float4 v = *(const float4*)(src + off);
    u16x4 o;
    o[0] = f2bf(v.x); o[1] = f2bf(v.y); o[2] = f2bf(v.z); o[3] = f2bf(v.w);
    *(u16x4*)(dst + i) = o;
}

// ---------------- concat 3 bias vectors into [3072] ----------------
__global__ void concat_bias(const float* __restrict__ qb, const float* __restrict__ kb,
                            const float* __restrict__ vb, float* __restrict__ o) {
    int i = blockIdx.x * blockDim.x + threadIdx.x;
    if (i < DDIM) o[i] = qb[i];
    else if (i < DDIM + NKV) o[i] = kb[i - DDIM];
    else if (i < NQKV) o[i] = vb[i - DDIM - NKV];
}

// ---------------- vectorized RoPE in-place on qkv cols [0,2560), one launch ----------------
__global__ void rope_v(unsigned short* __restrict__ buf,
                       const float* __restrict__ cosT, const float* __restrict__ sinT,
                       float qscale) {
    int r = blockIdx.x, pos = r & (SDIM - 1);
    int col0 = threadIdx.x * 8;                 // 320 threads -> cols [0,2560)
    unsigned short* p = buf + (size_t)r * NQKV + col0;
    int i0 = (col0 & 127) >> 1;                 // pair index within head
    float4 c4 = *(const float4*)(cosT + pos * 64 + i0);
    float4 s4 = *(const float4*)(sinT + pos * 64 + i0);
    float sc = (col0 < DDIM) ? qscale : 1.f;
    u16x8 v = *(const u16x8*)p;
    u16x8 o;
    float cc[4] = {c4.x, c4.y, c4.z, c4.w}, ss[4] = {s4.x, s4.y, s4.z, s4.w};
#pragma unroll
    for (int k = 0; k < 4; ++k) {
        float xr = bf2f(v[2 * k]), xi = bf2f(v[2 * k + 1]);
        o[2 * k]     = f2bf((xr * cc[k] - xi * ss[k]) * sc);
        o[2 * k + 1] = f2bf((xr * ss[k] + xi * cc[k]) * sc);
    }
    *(u16x8*)p = o;
}

// ---------------- transpose V with sigma-permuted kv order within 32-chunks ----------------
// sigma: storage pos p for kv s (within 32): p = (Q<<3)|(u<<2)|r where s = (u<<4)|(Q<<2)|r
__global__ void transpose_v(const unsigned short* __restrict__ qkv,
                            unsigned short* __restrict__ Vt) {
    __shared__ unsigned short T[32][33];
    int s0 = blockIdx.x * 32, d0 = blockIdx.y * 32, b = blockIdx.z;
    int c = threadIdx.x & 31, r4 = threadIdx.x >> 5;
    for (int rr = r4; rr < 32; rr += 8)
        T[rr][c] = qkv[(size_t)(b * SDIM + s0 + rr) * NQKV + (DDIM + NKV) + d0 + c];
    __syncthreads();
    int cp = ((c & 0x0C) << 1) | ((c & 0x10) >> 2) | (c & 3);
    for (int rr = r4; rr < 32; rr += 8)
        Vt[(size_t)(b * NKV + d0 + rr) * SDIM + s0 + cp] = T[c][rr];
}

// ---------------- GEMM: C[M,N] = A[M,K] * B[N,K]^T + bias (m97 recipe) ----------------
template <int BF16OUT>
__global__ __launch_bounds__(256) void gemm_bt(
    const unsigned short* __restrict__ A,
    const unsigned short* __restrict__ Bm,
    const float* __restrict__ bias,
    void* __restrict__ Cv,
    int Ndim, int Kdim) {
    __shared__ unsigned short As[128 * 32];
    __shared__ unsigned short Bs[128 * 32];
    const int tid = threadIdx.x;
    const int w = tid >> 6, lane = tid & 63;
    const int ml = lane & 15, quad = lane >> 4;
    const int m0 = blockIdx.y * 128, n0 = blockIdx.x * 128;
    const int wr = (w >> 1) * 64, wc = (w & 1) * 64;

    f32x4 acc[4][4] = {};

    const int c0 = tid, c1 = tid + 256;
    const int ar0 = c0 >> 2, ak0 = (c0 & 3) * 8;
    const int ar1 = c1 >> 2, ak1 = (c1 & 3) * 8;

    for (int kt = 0; kt < Kdim; kt += 32) {
        __builtin_amdgcn_global_load_lds(
            (const AS1 unsigned int*)(A + (size_t)(m0 + ar0) * Kdim + kt + ak0),
            (AS3 unsigned int*)(As + c0 * 8), 16, 0, 0);
        __builtin_amdgcn_global_load_lds(
            (const AS1 unsigned int*)(A + (size_t)(m0 + ar1) * Kdim + kt + ak1),
            (AS3 unsigned int*)(As + c1 * 8), 16, 0, 0);
        __builtin_amdgcn_global_load_lds(
            (const AS1 unsigned int*)(Bm + (size_t)(n0 + ar0) * Kdim + kt + ak0),
            (AS3 unsigned int*)(Bs + c0 * 8), 16, 0, 0);
        __builtin_amdgcn_global_load_lds(
            (const AS1 unsigned int*)(Bm + (size_t)(n0 + ar1) * Kdim + kt + ak1),
            (AS3 unsigned int*)(Bs + c1 * 8), 16, 0, 0);
        __syncthreads();

        bf16x8 af[4], bfr[4];
#pragma unroll
        for (int i = 0; i < 4; ++i)
            af[i] = *(const bf16x8*)&As[(wr + i * 16 + ml) * 32 + quad * 8];
#pragma unroll
        for (int j = 0; j < 4; ++j)
            bfr[j] = *(const bf16x8*)&Bs[(wc + j * 16 + ml) * 32 + quad * 8];
#pragma unroll
        for (int i = 0; i < 4; ++i)
#pragma unroll
            for (int j = 0; j < 4; ++j)
                acc[i][j] = __builtin_amdgcn_mfma_f32_16x16x32_bf16(af[i], bfr[j], acc[i][j], 0, 0, 0);
        __syncthreads();
    }

#pragma unroll
    for (int j = 0; j < 4; ++j) {
        int col = n0 + wc + j * 16 + ml;
        float bj = bias[col];
#pragma unroll
        for (int i = 0; i < 4; ++i) {
            int row0 = m0 + wr + i * 16 + quad * 4;
#pragma unroll
            for (int r = 0; r < 4; ++r) {
                float v = acc[i][j][r] + bj;
                if (BF16OUT)
                    ((unsigned short*)Cv)[(size_t)(row0 + r) * Ndim + col] = f2bf(v);
                else
                    ((float*)Cv)[(size_t)(row0 + r) * Ndim + col] = v;
            }
        }
    }
}

// ---------------- Flash attention: S^T formulation, zero P round-trip ----------------
// S^T = K·Q^T (lane: q=ml, kv=16t+4*quad+r). P^T B-frag = lane's own regs under sigma.
// O^T accumulated (m=d, n=q). Vt is sigma-permuted within 32-chunks.
__global__ __launch_bounds__(256, 2) void attn_fwd(
    const unsigned short* __restrict__ Qp,
    const unsigned short* __restrict__ Kp,
    const unsigned short* __restrict__ Vt,
    unsigned short* __restrict__ O) {
    const int l = blockIdx.x;
    const int qt = (l < 256) ? (15 - (l >> 5)) : ((l - 256) >> 5);  // balanced pairing
    const int h = l & 15;
    const int b = (l >> 4) & 1;
    const int g = h >> 2;
    const int tid = threadIdx.x;
    const int w = tid >> 6, lane = tid & 63;
    const int ml = lane & 15, quad = lane >> 4;
    const int seg = lane & 3, rsub = lane >> 2;

    __shared__ unsigned short Ks[4 * 64 * 32];   // [kc][krow][32]
    __shared__ unsigned short Vs[2 * 128 * 32];  // [kv32-chunk][d][32] (sigma order)

    // Q B-frags (n=q=ml, k=quad*8+j), wave w owns q rows q0..q0+31
    bf16x8 aq[2][4];
#pragma unroll
    for (int g2 = 0; g2 < 2; ++g2) {
        const size_t qrow = (size_t)(b * SDIM + qt * 128 + w * 32 + g2 * 16 + ml);
#pragma unroll
        for (int kc = 0; kc < 4; ++kc)
            aq[g2][kc] = *(const bf16x8*)(Qp + qrow * NQKV + h * DKH + kc * 32 + quad * 8);
    }

    f32x4 o_acc[2][8] = {};
    float m_run[2] = {-INFINITY, -INFINITY}, l_run[2] = {0.f, 0.f};
    const int q0 = qt * 128 + w * 32;
    const int ktend = 2 * qt + 2;

    for (int kt = 0; kt < ktend; ++kt) {
        const int kb = kt * 64;
        __syncthreads();
        // stage K tile (64 x 128)
#pragma unroll
        for (int kc = 0; kc < 4; ++kc)
            __builtin_amdgcn_global_load_lds(
                (const AS1 unsigned int*)(Kp + (size_t)(b * SDIM + kb + w * 16 + rsub) * NQKV + g * DKH + kc * 32 + seg * 8),
                (AS3 unsigned int*)(Ks + kc * 2048 + w * 512 + lane * 8), 16, 0, 0);
        // stage V^T tile (128 d x 64 kv, sigma-ordered)
#pragma unroll
        for (int c = 0; c < 4; ++c) {
            int u = w * 4 + c, kc2 = u >> 3, rg = u & 7;
            __builtin_amdgcn_global_load_lds(
                (const AS1 unsigned int*)(Vt + (size_t)(b * NKV + g * DKH + rg * 16 + rsub) * SDIM + kb + kc2 * 32 + seg * 8),
                (AS3 unsigned int*)(Vs + u * 512 + lane * 8), 16, 0, 0);
        }
        __syncthreads();

        if (kb <= q0 + 31) {
            // S^T: A=K (m=kv), B=Q (n=q). st[g2][t][r] at kv=kb+16t+4*quad+r, q=q0+g2*16+ml
            f32x4 st[2][4];
#pragma unroll
            for (int t = 0; t < 4; ++t) {
                bf16x8 ak[4];
#pragma unroll
                for (int kc = 0; kc < 4; ++kc)
                    ak[kc] = *(const bf16x8*)&Ks[kc * 2048 + (t * 16 + ml) * 32 + quad * 8];
#pragma unroll
                for (int g2 = 0; g2 < 2; ++g2) {
                    f32x4 sc = {};
#pragma unroll
                    for (int kc = 0; kc < 4; ++kc)
                        sc = __builtin_amdgcn_mfma_f32_16x16x32_bf16(ak[kc], aq[g2][kc], sc, 0, 0, 0);
                    st[g2][t] = sc;
                }
            }

            const bool diag = (kb + 63 > q0);
            float mx[2] = {-INFINITY, -INFINITY};
            if (diag) {
#pragma unroll
                for (int g2 = 0; g2 < 2; ++g2) {
                    int qg = q0 + g2 * 16 + ml;
#pragma unroll
                    for (int t = 0; t < 4; ++t) {
                        int kvb = kb + t * 16 + quad * 4;
#pragma unroll
                        for (int r = 0; r < 4; ++r) {
                            float x = st[g2][t][r];
                            if (kvb + r > qg) x = -INFINITY;
                            st[g2][t][r] = x;
                            mx[g2] = fmaxf(mx[g2], x);
                        }
                    }
                }
            } else {
#pragma unroll
                for (int g2 = 0; g2 < 2; ++g2)
#pragma unroll
                    for (int t = 0; t < 4; ++t)
#pragma unroll
                        for (int r = 0; r < 4; ++r)
                            mx[g2] = fmaxf(mx[g2], st[g2][t][r]);
            }
            // row (q) reduction: only across quads (lanes ml, ml+16, ml+32, ml+48)
#pragma unroll
            for (int g2 = 0; g2 < 2; ++g2) {
                float m = mx[g2];
                m = fmaxf(m, __shfl_xor(m, 16));
                m = fmaxf(m, __shfl_xor(m, 32));
                float m_new = fmaxf(m_run[g2], m);
                float alpha = __expf(m_run[g2] - m_new);
                m_run[g2] = m_new;

                float lad = 0.f;
                unsigned int pk[4][2];
#pragma unroll
                for (int t = 0; t < 4; ++t) {
                    float p0 = __expf(st[g2][t][0] - m_new);
                    float p1 = __expf(st[g2][t][1] - m_new);
                    float p2 = __expf(st[g2][t][2] - m_new);
                    float p3 = __expf(st[g2][t][3] - m_new);
                    lad += (p0 + p1) + (p2 + p3);
                    pk[t][0] = pack2bf(p0, p1);
                    pk[t][1] = pack2bf(p2, p3);
                }
                lad += __shfl_xor(lad, 16);
                lad += __shfl_xor(lad, 32);
                l_run[g2] = l_run[g2] * alpha + lad;

#pragma unroll
                for (int dt = 0; dt < 8; ++dt)
#pragma unroll
                    for (int r = 0; r < 4; ++r)
                        o_acc[g2][dt][r] *= alpha;

                // PV: O^T += V^T · P^T ; B-frag of P^T = in-lane pk regs (sigma order)
#pragma unroll
                for (int c = 0; c < 2; ++c) {
                    union { unsigned int u[4]; bf16x8 v; } pb;
                    pb.u[0] = pk[2 * c][0];  pb.u[1] = pk[2 * c][1];
                    pb.u[2] = pk[2 * c + 1][0]; pb.u[3] = pk[2 * c + 1][1];
#pragma unroll
                    for (int dt = 0; dt < 8; ++dt) {
                        bf16x8 av = *(const bf16x8*)&Vs[c * 4096 + (dt * 16 + ml) * 32 + quad * 8];
                        o_acc[g2][dt] = __builtin_amdgcn_mfma_f32_16x16x32_bf16(av, pb.v, o_acc[g2][dt], 0, 0, 0);
                    }
                }
            }
        }
    }

    // epilogue: O^T layout -> O[q][d], 8B packed stores
#pragma unroll
    for (int g2 = 0; g2 < 2; ++g2) {
        float inv = 1.f / l_run[g2];
        size_t rowbase = (size_t)(b * SDIM + q0 + g2 * 16 + ml) * DDIM + h * DKH + quad * 4;
#pragma unroll
        for (int dt = 0; dt < 8; ++dt) {
            u16x4 ov;
#pragma unroll
            for (int r = 0; r < 4; ++r)
                ov[r] = f2bf(o_acc[g2][dt][r] * inv);
            *(u16x4*)(O + rowbase + dt * 16) = ov;
        }
    }
}

// ---------------- host launch ----------------
extern "C" void kernel_launch(void* const* d_in, const int* in_sizes, int n_in,
                              void* d_out, int out_size, void* d_ws, size_t ws_size,
                              hipStream_t stream) {
    const float* x    = (const float*)d_in[0];
    const float* fcos = (const float*)d_in[1];
    const float* fsin = (const float*)d_in[2];
    const float* wq_w = (const float*)d_in[3];
    const float* wq_b = (const float*)d_in[4];
    const float* wk_w = (const float*)d_in[5];
    const float* wk_b = (const float*)d_in[6];
    const float* wv_w = (const float*)d_in[7];
    const float* wv_b = (const float*)d_in[8];
    const float* wo_w = (const float*)d_in[9];
    const float* wo_b = (const float*)d_in[10];
    float* out = (float*)d_out;

    char* ws = (char*)d_ws;
    size_t off = 0;
    auto alloc = [&](size_t bytes) {
        char* p = ws + off;
        off += (bytes + 255) & ~(size_t)255;
        return p;
    };
    // NOTE: xb|W3|wob must be contiguous (cast_all writes them as one range)
    unsigned short* xb  = (unsigned short*)alloc(NX * 2);
    unsigned short* W3  = (unsigned short*)alloc((size_t)NQKV * DDIM * 2);
    unsigned short* wob = (unsigned short*)alloc(NWQ * 2);
    float* b3           = (float*)alloc((size_t)NQKV * 4);
    unsigned short* qkv = (unsigned short*)alloc((size_t)MROWS * NQKV * 2);
    unsigned short* Vt  = (unsigned short*)alloc((size_t)BDIM * NKV * SDIM * 2);
    unsigned short* att = (unsigned short*)alloc((size_t)MROWS * DDIM * 2);

    const size_t total4 = (NX + 2 * NWQ + 2 * NWKV) / 4;     // 4718592
    cast_all<<<dim3((unsigned)((total4 + 255) / 256)), dim3(256), 0, stream>>>(x, wq_w, wk_w, wv_w, wo_w, xb);
    concat_bias<<<dim3(12), dim3(256), 0, stream>>>(wq_b, wk_b, wv_b, b3);

    // fused QKV projection: [4096,3072] bf16
    gemm_bt<1><<<dim3(NQKV / 128, MROWS / 128), 256, 0, stream>>>(xb, W3, b3, qkv, NQKV, DDIM);

    const float scale = 0.08838834764831845f;  // 1/sqrt(128), folded into Q
    rope_v<<<dim3(MROWS), dim3(320), 0, stream>>>(qkv, fcos, fsin, scale);
    transpose_v<<<dim3(SDIM / 32, NKV / 32, BDIM), 256, 0, stream>>>(qkv, Vt);

    attn_fwd<<<dim3(512), dim3(256), 0, stream>>>(qkv, qkv + DDIM, Vt, att);

    // output projection (f32 out)
    gemm_bt<0><<<dim3(DDIM / 128, MROWS / 128), 256, 0, stream>>>(att, wob, wo_b, out, DDIM, DDIM);
}